// Round 5
// baseline (686.611 us; speedup 1.0000x reference)
//
#include <hip/hip_runtime.h>

#define F_IN 61
#define H 32

// ---------- degree / dinv ----------
__global__ __launch_bounds__(256) void deg_kernel(const int* __restrict__ ei,
                                                  int* __restrict__ deg, int E) {
    int e = blockIdx.x * 256 + threadIdx.x;
    if (e < E) atomicAdd(&deg[ei[E + e]], 1);
}

__global__ __launch_bounds__(256) void dinv_kernel(const int* __restrict__ deg,
                                                   float* __restrict__ dinv, int N) {
    int i = blockIdx.x * 256 + threadIdx.x;
    if (i < N) dinv[i] = rsqrtf((float)deg[i] + 1.0f);   // +1 self-loop
}

// ---------- exclusive scan over deg (3 kernels) ----------
__global__ __launch_bounds__(256) void scan1_kernel(const int* __restrict__ deg,
                                                    int* __restrict__ scanned,
                                                    int* __restrict__ btot, int N) {
    __shared__ int s[256];
    int tid = threadIdx.x;
    int i = blockIdx.x * 256 + tid;
    int v = (i < N) ? deg[i] : 0;
    s[tid] = v;
    __syncthreads();
    for (int off = 1; off < 256; off <<= 1) {
        int t = (tid >= off) ? s[tid - off] : 0;
        __syncthreads();
        s[tid] += t;
        __syncthreads();
    }
    if (i < N) scanned[i] = s[tid] - v;
    if (tid == 255) btot[blockIdx.x] = s[255];
}

__global__ __launch_bounds__(1024) void scan2_kernel(int* __restrict__ btot, int nB) {
    __shared__ int s[1024];
    int tid = threadIdx.x;
    int v = (tid < nB) ? btot[tid] : 0;
    s[tid] = v;
    __syncthreads();
    for (int off = 1; off < 1024; off <<= 1) {
        int t = (tid >= off) ? s[tid - off] : 0;
        __syncthreads();
        s[tid] += t;
        __syncthreads();
    }
    if (tid < nB) btot[tid] = s[tid] - v;
}

__global__ __launch_bounds__(256) void scan3_kernel(const int* __restrict__ scanned,
                                                    const int* __restrict__ btot,
                                                    int* __restrict__ row_start, int N, int E) {
    int i = blockIdx.x * 256 + threadIdx.x;
    if (i < N) row_start[i] = scanned[i] + btot[blockIdx.x];
    if (i == 0) row_start[N] = E;
}

// ---------- scatter: one int2 (src, norm) store per edge ----------
// Per-node cursors (150k counters, ~16-deep atomic chains). Single 8B store
// touches ONE 64B line per edge (vs 2 with separate src/norm arrays).
__global__ __launch_bounds__(256) void scatter_kernel(const int* __restrict__ ei,
                                                      const int* __restrict__ row_start,
                                                      int* __restrict__ cursor,
                                                      const float* __restrict__ dinv,
                                                      int2* __restrict__ pay, int E) {
    int e = blockIdx.x * 256 + threadIdx.x;
    if (e < E) {
        int s = ei[e];
        int d = ei[E + e];
        int pos = row_start[d] + atomicAdd(&cursor[d], 1);
        pay[pos] = make_int2(s, __float_as_int(dinv[s] * dinv[d]));
    }
}

// ---------- layer 1 dense: x(N x 61) @ W1 -> h1 ----------
__global__ __launch_bounds__(256) void gemm1_kernel(const float* __restrict__ x,
                                                    const float* __restrict__ W,
                                                    float* __restrict__ h, int N) {
    __shared__ float Ws[F_IN * H];
    __shared__ float xs[8 * F_IN];
    int tid = threadIdx.x;
    for (int i = tid; i < F_IN * H; i += 256) Ws[i] = W[i];
    int nb = blockIdx.x * 8;
    int navail = N - nb; if (navail > 8) navail = 8;
    const float* xb = x + (long long)nb * F_IN;
    for (int i = tid; i < navail * F_IN; i += 256) xs[i] = xb[i];
    __syncthreads();
    int nl = tid >> 5, f = tid & 31;
    int node = nb + nl;
    if (node < N) {
        float s = 0.f;
        #pragma unroll
        for (int k = 0; k < F_IN; k++) s += xs[nl * F_IN + k] * Ws[k * H + f];
        h[(long long)node * H + f] = s;
    }
}

// ---------- fused agg + GEMM ----------
// One 64-lane wave per node. lane = (j = lane>>3 edge slot, q = lane&7 feature
// quad). Each lane float4-gathers quad q of edge j's src row -> 8 row-requests
// in flight per instruction. Butterfly-reduce over j, lanes 0..7 finalize
// (self-loop + bias + relu) into LDS, then block GEMM X @ Wn.
__global__ __launch_bounds__(256) void agg_gemm_kernel(const int* __restrict__ row_start,
                                                       const int2* __restrict__ pay,
                                                       const float* __restrict__ dinv,
                                                       const float* __restrict__ h,
                                                       const float* __restrict__ b,
                                                       const float* __restrict__ Wn,
                                                       float* __restrict__ hout, int N) {
    __shared__ float Ws[H * H];
    __shared__ float t[4 * H];
    int tid = threadIdx.x;
    for (int i = tid; i < H * H; i += 256) Ws[i] = Wn[i];
    int wave = tid >> 6;
    int lane = tid & 63;
    int j = lane >> 3;       // edge slot 0..7
    int q = lane & 7;        // feature quad 0..7
    int node = blockIdx.x * 4 + wave;
    float4 acc = make_float4(0.f, 0.f, 0.f, 0.f);
    if (node < N) {
        int e0 = row_start[node], e1 = row_start[node + 1];
        for (int e = e0 + j; e < e1; e += 8) {
            int2 p = pay[e];
            float w = __int_as_float(p.y);
            float4 hv = ((const float4*)(h + (long long)p.x * H))[q];
            acc.x += hv.x * w; acc.y += hv.y * w;
            acc.z += hv.z * w; acc.w += hv.w * w;
        }
    }
    #pragma unroll
    for (int m = 8; m <= 32; m <<= 1) {
        acc.x += __shfl_xor(acc.x, m);
        acc.y += __shfl_xor(acc.y, m);
        acc.z += __shfl_xor(acc.z, m);
        acc.w += __shfl_xor(acc.w, m);
    }
    if (j == 0) {
        float4 r = make_float4(0.f, 0.f, 0.f, 0.f);
        if (node < N) {
            float di = dinv[node];
            float s2 = di * di;
            float4 hv = ((const float4*)(h + (long long)node * H))[q];
            float4 bv = ((const float4*)b)[q];
            r.x = fmaxf(acc.x + hv.x * s2 + bv.x, 0.f);
            r.y = fmaxf(acc.y + hv.y * s2 + bv.y, 0.f);
            r.z = fmaxf(acc.z + hv.z * s2 + bv.z, 0.f);
            r.w = fmaxf(acc.w + hv.w * s2 + bv.w, 0.f);
        }
        ((float4*)&t[wave * H])[q] = r;
    }
    __syncthreads();
    if (tid < 128) {
        int n = tid >> 5, f = tid & 31;
        int nd = blockIdx.x * 4 + n;
        if (nd < N) {
            float s = 0.f;
            #pragma unroll
            for (int k = 0; k < H; k++) s += t[n * H + k] * Ws[k * H + f];
            hout[(long long)nd * H + f] = s;
        }
    }
}

// ---------- final layer: X5 = relu(agg(h4)+b4); pool into 64 spread copies ----------
__global__ __launch_bounds__(256) void agg_pool_kernel(const int* __restrict__ row_start,
                                                       const int2* __restrict__ pay,
                                                       const float* __restrict__ dinv,
                                                       const float* __restrict__ h,
                                                       const float* __restrict__ b,
                                                       float* __restrict__ gs, int N) {
    __shared__ float t[4 * H];
    int tid = threadIdx.x;
    int wave = tid >> 6;
    int lane = tid & 63;
    int j = lane >> 3;
    int q = lane & 7;
    int node = blockIdx.x * 4 + wave;
    float4 acc = make_float4(0.f, 0.f, 0.f, 0.f);
    if (node < N) {
        int e0 = row_start[node], e1 = row_start[node + 1];
        for (int e = e0 + j; e < e1; e += 8) {
            int2 p = pay[e];
            float w = __int_as_float(p.y);
            float4 hv = ((const float4*)(h + (long long)p.x * H))[q];
            acc.x += hv.x * w; acc.y += hv.y * w;
            acc.z += hv.z * w; acc.w += hv.w * w;
        }
    }
    #pragma unroll
    for (int m = 8; m <= 32; m <<= 1) {
        acc.x += __shfl_xor(acc.x, m);
        acc.y += __shfl_xor(acc.y, m);
        acc.z += __shfl_xor(acc.z, m);
        acc.w += __shfl_xor(acc.w, m);
    }
    if (j == 0) {
        float4 r = make_float4(0.f, 0.f, 0.f, 0.f);
        if (node < N) {
            float di = dinv[node];
            float s2 = di * di;
            float4 hv = ((const float4*)(h + (long long)node * H))[q];
            float4 bv = ((const float4*)b)[q];
            r.x = fmaxf(acc.x + hv.x * s2 + bv.x, 0.f);
            r.y = fmaxf(acc.y + hv.y * s2 + bv.y, 0.f);
            r.z = fmaxf(acc.z + hv.z * s2 + bv.z, 0.f);
            r.w = fmaxf(acc.w + hv.w * s2 + bv.w, 0.f);
        }
        ((float4*)&t[wave * H])[q] = r;
    }
    __syncthreads();
    if (tid < H) {
        float s = t[tid] + t[H + tid] + t[2 * H + tid] + t[3 * H + tid];
        atomicAdd(&gs[(blockIdx.x & 63) * H + tid], s);
    }
}

// ---------- head: reduce 64 pool copies, 32->16 relu, 16->3 ----------
__global__ __launch_bounds__(64) void head_kernel(const float* __restrict__ gs,
                                                  const float* __restrict__ Wl1,
                                                  const float* __restrict__ bl1,
                                                  const float* __restrict__ Wl2,
                                                  const float* __restrict__ bl2,
                                                  float* __restrict__ out) {
    __shared__ float gg[H];
    __shared__ float t[16];
    int tid = threadIdx.x;
    if (tid < H) {
        float s = 0.f;
        for (int c = 0; c < 64; c++) s += gs[c * H + tid];
        gg[tid] = s;
    }
    __syncthreads();
    if (tid < 16) {
        float s = bl1[tid];
        #pragma unroll
        for (int k = 0; k < 32; k++) s += gg[k] * Wl1[k * 16 + tid];
        t[tid] = fmaxf(s, 0.f);
    }
    __syncthreads();
    if (tid < 3) {
        float s = bl2[tid];
        #pragma unroll
        for (int k = 0; k < 16; k++) s += t[k] * Wl2[k * 3 + tid];
        out[tid] = s;
    }
}

extern "C" void kernel_launch(void* const* d_in, const int* in_sizes, int n_in,
                              void* d_out, int out_size, void* d_ws, size_t ws_size,
                              hipStream_t stream) {
    const float* x   = (const float*)d_in[0];
    const int*   ei  = (const int*)d_in[1];
    const float* W1  = (const float*)d_in[2];
    const float* b1  = (const float*)d_in[3];
    const float* W2  = (const float*)d_in[4];
    const float* b2  = (const float*)d_in[5];
    const float* W3  = (const float*)d_in[6];
    const float* b3  = (const float*)d_in[7];
    const float* W4  = (const float*)d_in[8];
    const float* b4  = (const float*)d_in[9];
    const float* Wl1 = (const float*)d_in[10];
    const float* bl1 = (const float*)d_in[11];
    const float* Wl2 = (const float*)d_in[12];
    const float* bl2 = (const float*)d_in[13];
    float* out = (float*)d_out;

    const int N = in_sizes[0] / F_IN;
    const int E = in_sizes[1] / 2;

    char* ws = (char*)d_ws;
    size_t off = 0;
    auto alloc = [&](size_t bytes) {
        char* p = ws + off;
        off += (bytes + 255) & ~(size_t)255;
        return p;
    };
    int*   deg       = (int*)alloc((size_t)N * 4);
    float* dinv      = (float*)alloc((size_t)N * 4);
    int*   scanned   = (int*)alloc((size_t)N * 4);
    int*   btot      = (int*)alloc(((size_t)N / 256 + 2) * 4);
    int*   row_start = (int*)alloc((size_t)(N + 1) * 4);
    int*   cursor    = (int*)alloc((size_t)N * 4);
    int2*  pay       = (int2*)alloc((size_t)E * 8);
    float* bufA      = (float*)alloc((size_t)N * H * 4);
    float* bufB      = (float*)alloc((size_t)N * H * 4);
    float* gs        = (float*)alloc(64 * H * 4);

    const int TB = 256;
    const int gE  = (E + TB - 1) / TB;
    const int gN  = (N + TB - 1) / TB;   // scan blocks (<=1024 for N<=262144)
    const int gN8 = (N + 7) / 8;
    const int gN4 = (N + 3) / 4;

    // ---- CSR build ----
    hipMemsetAsync(deg, 0, (size_t)N * 4, stream);
    hipMemsetAsync(cursor, 0, (size_t)N * 4, stream);
    hipMemsetAsync(gs, 0, 64 * H * 4, stream);
    deg_kernel<<<gE, TB, 0, stream>>>(ei, deg, E);
    dinv_kernel<<<gN, TB, 0, stream>>>(deg, dinv, N);
    scan1_kernel<<<gN, TB, 0, stream>>>(deg, scanned, btot, N);
    scan2_kernel<<<1, 1024, 0, stream>>>(btot, gN);
    scan3_kernel<<<gN, TB, 0, stream>>>(scanned, btot, row_start, N, E);
    scatter_kernel<<<gE, TB, 0, stream>>>(ei, row_start, cursor, dinv, pay, E);

    // ---- layers ----
    gemm1_kernel<<<gN8, TB, 0, stream>>>(x, W1, bufA, N);                        // h1
    agg_gemm_kernel<<<gN4, TB, 0, stream>>>(row_start, pay, dinv, bufA, b1, W2, bufB, N); // h2
    agg_gemm_kernel<<<gN4, TB, 0, stream>>>(row_start, pay, dinv, bufB, b2, W3, bufA, N); // h3
    agg_gemm_kernel<<<gN4, TB, 0, stream>>>(row_start, pay, dinv, bufA, b3, W4, bufB, N); // h4
    agg_pool_kernel<<<gN4, TB, 0, stream>>>(row_start, pay, dinv, bufB, b4, gs, N);       // pool(X5)

    head_kernel<<<1, 64, 0, stream>>>(gs, Wl1, bl1, Wl2, bl2, out);
}